// Round 6
// baseline (8961.945 us; speedup 1.0000x reference)
//
#include <hip/hip_runtime.h>
#include <hip/hip_cooperative_groups.h>

namespace cg = cooperative_groups;

#define T_  512
#define B_  64
#define F_  256
#define E_  512
#define AGENT __HIP_MEMORY_SCOPE_AGENT
#define P64 0xAAAAAAAAAAAAAAAAull

typedef __bf16 bf16x8 __attribute__((ext_vector_type(8)));
typedef float  f32x4  __attribute__((ext_vector_type(4)));

// ---- ws layout (bytes). Write-once rings, B-MAJOR: ring[t][b][dim] bf16.
// DATA-AS-FLAG: rings are 0xAA-poisoned before every launch; producers store
// atomic u64 chunks (sc1, fabric); consumers poll the u64s directly against
// the poison pattern. A written u64 == poison requires 4 bf16 values each
// exactly 0xAAAA (~impossible). No per-step flags, drains, or slot polls.
#define OFF_HF   0ull                    // [T+1][B][E] bf16 = 33,619,968
#define OFF_HB   33619968ull             // [T+1][B][E] bf16
#define OFF_HD   67239936ull             // [T+1][B][F] bf16 = 16,809,984
#define OFF_XP   84049920ull             // [4F][B] f32 = 262,144
#define OFF_SL   84312064ull             // join slots: J[128], X[128]

// ---- LDS arena (bytes); weights live here for the whole kernel ----
#define L_WHH_H 0        // ushort[32][520]
#define L_WHH_L 33280
#define L_WIH_H 66560    // ushort[32][264]
#define L_WIH_L 83456
#define L_DWH_H 100352   // ushort[16][264]
#define L_DWH_L 108800
#define L_PRE   117248   // float[32][68]  (decoder: [2][16][68])
#define L_HPACK 125952   // ushort[64][8]
#define L_TOTAL 126976
#define LDK_H 520
#define LDK_X 264
#define LDP   68

__device__ __forceinline__ float sigmoidf_(float x) {
    return 1.0f / (1.0f + __expf(-x));
}
__device__ __forceinline__ float tanhf_(float x) {
    float xc = fminf(fmaxf(x, -15.0f), 15.0f);
    float e = __expf(2.0f * xc);
    return (e - 1.0f) / (e + 1.0f);
}
__device__ __forceinline__ unsigned short f2bf(float f) {   // RNE
    unsigned u = __float_as_uint(f);
    u += 0x7fffu + ((u >> 16) & 1u);
    return (unsigned short)(u >> 16);
}
__device__ __forceinline__ float bfbits2f(unsigned us) {
    return __uint_as_float(us << 16);
}
__device__ __forceinline__ void astore_u32(unsigned* p, unsigned v) {
    __hip_atomic_store(p, v, __ATOMIC_RELAXED, AGENT);
}
__device__ __forceinline__ unsigned aload_u32(const unsigned* p) {
    return __hip_atomic_load(p, __ATOMIC_RELAXED, AGENT);
}
__device__ __forceinline__ void astore_u64(unsigned long long* p, unsigned long long v) {
    __hip_atomic_store(p, v, __ATOMIC_RELAXED, AGENT);
}
__device__ __forceinline__ unsigned long long aload_u64(const unsigned long long* p) {
    return __hip_atomic_load(p, __ATOMIC_RELAXED, AGENT);
}
__device__ __forceinline__ void astore_f(float* p, float v) {
    __hip_atomic_store(p, v, __ATOMIC_RELAXED, AGENT);
}
__device__ __forceinline__ bf16x8 mk_bf16x8(unsigned long long q0, unsigned long long q1) {
    uint4 q = { (unsigned)q0, (unsigned)(q0 >> 32), (unsigned)q1, (unsigned)(q1 >> 32) };
    return __builtin_bit_cast(bf16x8, q);
}

__global__ __launch_bounds__(512, 1)
void autoenc_kernel(const float* __restrict__ seq,
                    const float* __restrict__ WihF, const float* __restrict__ WhhF, const float* __restrict__ bF,
                    const float* __restrict__ WihB, const float* __restrict__ WhhB, const float* __restrict__ bB,
                    const float* __restrict__ dWih, const float* __restrict__ dWhh, const float* __restrict__ db,
                    float* __restrict__ out, char* __restrict__ ws)
{
    cg::grid_group grid = cg::this_grid();
    const int tid = threadIdx.x;
    const int bid = blockIdx.x;

    unsigned short* hfR = (unsigned short*)(ws + OFF_HF);
    unsigned short* hbR = (unsigned short*)(ws + OFF_HB);
    unsigned short* hdR = (unsigned short*)(ws + OFF_HD);
    float* xp0T = (float*)(ws + OFF_XP);
    unsigned* slotsJ = (unsigned*)(ws + OFF_SL);   // [128] encoder-done join
    unsigned* slotsX = slotsJ + 128;               // [128] xp0-done join

    __shared__ __align__(16) char arena[L_TOTAL];
    unsigned short* whhH = (unsigned short*)(arena + L_WHH_H);
    unsigned short* whhL = (unsigned short*)(arena + L_WHH_L);
    unsigned short* wihH = (unsigned short*)(arena + L_WIH_H);
    unsigned short* wihL = (unsigned short*)(arena + L_WIH_L);
    unsigned short* dwhH = (unsigned short*)(arena + L_DWH_H);
    unsigned short* dwhL = (unsigned short*)(arena + L_DWH_L);
    float* pre = (float*)(arena + L_PRE);
    unsigned short* hpack = (unsigned short*)(arena + L_HPACK);

    const int dir = bid >> 6;          // 0 fwd (blocks 0..63), 1 bwd (64..127)
    const int blk = bid & 63;
    const int e0  = blk * 8;           // encoder block owns h dims [e0, e0+8)
    const float* Wih  = dir ? WihB : WihF;
    const float* Whh  = dir ? WhhB : WhhF;
    const float* bias = dir ? bB   : bF;
    unsigned short* ring = dir ? hbR : hfR;

    // ---- init: zero ring[0] slabs + join slots (sc1 only) ----
    {
        unsigned* hf0 = (unsigned*)hfR;
        unsigned* hb0 = (unsigned*)hbR;
        unsigned* hd0 = (unsigned*)hdR;
        for (int i = bid * 512 + tid; i < 16384; i += 128 * 512) { astore_u32(hf0 + i, 0u); astore_u32(hb0 + i, 0u); }
        for (int i = bid * 512 + tid; i < 8192;  i += 128 * 512) astore_u32(hd0 + i, 0u);
        if (bid == 0 && tid < 256) astore_u32(slotsJ + tid, 0u);
    }

    // ---- one-time weight conversion fp32 -> bf16 hi/lo in LDS ----
    for (int idx = tid; idx < 32 * 512; idx += 512) {        // Whh 32 rows x 512
        int r = idx >> 9, k = idx & 511;
        int grow = (r >> 3) * E_ + e0 + (r & 7);
        float w = Whh[(size_t)grow * E_ + k];
        __bf16 h16 = (__bf16)w;
        __bf16 l16 = (__bf16)(w - (float)h16);
        whhH[r * LDK_H + k] = __builtin_bit_cast(unsigned short, h16);
        whhL[r * LDK_H + k] = __builtin_bit_cast(unsigned short, l16);
    }
    for (int idx = tid; idx < 32 * 256; idx += 512) {        // Wih 32 rows x 256
        int r = idx >> 8, k = idx & 255;
        int grow = (r >> 3) * E_ + e0 + (r & 7);
        float w = Wih[(size_t)grow * F_ + k];
        __bf16 h16 = (__bf16)w;
        __bf16 l16 = (__bf16)(w - (float)h16);
        wihH[r * LDK_X + k] = __builtin_bit_cast(unsigned short, h16);
        wihL[r * LDK_X + k] = __builtin_bit_cast(unsigned short, l16);
    }
    if (bid < 64) {                                          // dec Whh 16 rows x 256
        const int fb0 = bid * 4;
        for (int idx = tid; idx < 16 * 256; idx += 512) {
            int r = idx >> 8, k = idx & 255;
            int grow = (r >> 2) * F_ + fb0 + (r & 3);
            float w = dWhh[(size_t)grow * F_ + k];
            __bf16 h16 = (__bf16)w;
            __bf16 l16 = (__bf16)(w - (float)h16);
            dwhH[r * LDK_X + k] = __builtin_bit_cast(unsigned short, h16);
            dwhL[r * LDK_X + k] = __builtin_bit_cast(unsigned short, l16);
        }
    }
    __syncthreads();
    grid.sync();   // one-time fence: ring[0]/slots visible everywhere

    const int w    = tid >> 6;        // wave 0..7
    const int lane = tid & 63;
    const int col  = lane & 15;
    const int quad = lane >> 4;

    // ================= encoder: bidirectional LSTM (MFMA) =================
    {
        const int mt = w & 1, nt = w >> 1;       // C-tile: rows [mt*16,+16) x b [nt*16,+16)
        const int bcol = nt * 16 + col;
        const unsigned short* aHh = whhH + (mt * 16 + col) * LDK_H + quad * 8;
        const unsigned short* aHl = whhL + (mt * 16 + col) * LDK_H + quad * 8;
        const unsigned short* aXh = wihH + (mt * 16 + col) * LDK_X + quad * 8;
        const unsigned short* aXl = wihL + (mt * 16 + col) * LDK_X + quad * 8;

        const int ej = tid & 7, eb = tid >> 3;   // epilogue (j, b)
        const float bGi = bias[0 * E_ + e0 + ej];
        const float bGf = bias[1 * E_ + e0 + ej];
        const float bGg = bias[2 * E_ + e0 + ej];
        const float bGo = bias[3 * E_ + e0 + ej];
        float creg = 0.0f;

        for (int t = 0; t < T_; ++t) {
            const int t_eff = dir ? (T_ - 1 - t) : t;
            f32x4 acc = {0.f, 0.f, 0.f, 0.f};

            // ---- x-part first (h-independent; hides producer->consumer RT) ----
            {
                const float* xrow = seq + (size_t)t_eff * B_ * F_ + bcol * F_ + quad * 8;
                #pragma unroll
                for (int kt = 0; kt < 8; ++kt) {
                    float4 v0 = *(const float4*)(xrow + kt * 32);
                    float4 v1 = *(const float4*)(xrow + kt * 32 + 4);
                    float vv[8] = {v0.x, v0.y, v0.z, v0.w, v1.x, v1.y, v1.z, v1.w};
                    bf16x8 xh, xl;
                    #pragma unroll
                    for (int j2 = 0; j2 < 8; ++j2) {
                        __bf16 hv = (__bf16)vv[j2];
                        xh[j2] = hv;
                        xl[j2] = (__bf16)(vv[j2] - (float)hv);
                    }
                    bf16x8 ah = *(const bf16x8*)(aXh + kt * 32);
                    bf16x8 al = *(const bf16x8*)(aXl + kt * 32);
                    acc = __builtin_amdgcn_mfma_f32_16x16x32_bf16(ah, xh, acc, 0, 0, 0);
                    acc = __builtin_amdgcn_mfma_f32_16x16x32_bf16(al, xh, acc, 0, 0, 0);
                    acc = __builtin_amdgcn_mfma_f32_16x16x32_bf16(ah, xl, acc, 0, 0, 0);
                }
            }

            // ---- h-part: batched polled loads (data-as-flag), then MFMAs ----
            {
                const unsigned long long* h64 = (const unsigned long long*)
                    (ring + (size_t)t * (B_ * E_) + bcol * E_ + quad * 8);
                unsigned long long hv[32];
                #pragma unroll
                for (int i = 0; i < 16; ++i) {
                    hv[2 * i]     = aload_u64(h64 + i * 8);
                    hv[2 * i + 1] = aload_u64(h64 + i * 8 + 1);
                }
                for (;;) {
                    bool ok = true;
                    #pragma unroll
                    for (int i = 0; i < 32; ++i) ok &= (hv[i] != P64);
                    if (ok) break;
                    #pragma unroll
                    for (int i = 0; i < 16; ++i) {
                        hv[2 * i]     = aload_u64(h64 + i * 8);
                        hv[2 * i + 1] = aload_u64(h64 + i * 8 + 1);
                    }
                }
                #pragma unroll
                for (int kt = 0; kt < 16; ++kt) {
                    bf16x8 hb = mk_bf16x8(hv[2 * kt], hv[2 * kt + 1]);
                    bf16x8 ah = *(const bf16x8*)(aHh + kt * 32);
                    bf16x8 al = *(const bf16x8*)(aHl + kt * 32);
                    acc = __builtin_amdgcn_mfma_f32_16x16x32_bf16(ah, hb, acc, 0, 0, 0);
                    acc = __builtin_amdgcn_mfma_f32_16x16x32_bf16(al, hb, acc, 0, 0, 0);
                }
            }
            // ---- dump C-frags ----
            #pragma unroll
            for (int rg = 0; rg < 4; ++rg)
                pre[(mt * 16 + quad * 4 + rg) * LDP + nt * 16 + col] = acc[rg];
            __syncthreads();

            // ---- epilogue ----
            {
                float gI = pre[(0 * 8 + ej) * LDP + eb] + bGi;
                float gF = pre[(1 * 8 + ej) * LDP + eb] + bGf;
                float gG = pre[(2 * 8 + ej) * LDP + eb] + bGg;
                float gO = pre[(3 * 8 + ej) * LDP + eb] + bGo;
                creg = sigmoidf_(gF) * creg + sigmoidf_(gI) * tanhf_(gG);
                float h = sigmoidf_(gO) * tanhf_(creg);
                hpack[eb * 8 + ej] = f2bf(h);
            }
            __syncthreads();
            if (tid < 128) {     // fire-and-forget: the store IS the signal
                const int erow = tid >> 1, half = tid & 1;
                unsigned long long* dst = (unsigned long long*)
                    (ring + (size_t)(t + 1) * (B_ * E_) + erow * E_ + e0) + half;
                astore_u64(dst, ((const unsigned long long*)hpack)[tid]);
            }
        }
        // one-time join: drain final stores, flag, wait for all 128 blocks
        __syncthreads();
        if (tid == 0) astore_u32(slotsJ + bid, 1u);
        if (tid < 64) {
            bool ok;
            do {
                ok = (aload_u32(slotsJ + tid) != 0u) && (aload_u32(slotsJ + 64 + tid) != 0u);
            } while (!__all(ok));
        }
        __syncthreads();
    }

    // ================= xp0 = [h_f | h_b] @ dec_Wih^T + dec_b =================
    {
        const int r8 = tid >> 6, xb = tid & 63;
        const int r = bid * 8 + r8;                       // 0..1023
        const float* wr = dWih + (size_t)r * (2 * E_);
        float accv = db[r];
        const unsigned short* hf_ = hfR + (size_t)T_ * (B_ * E_) + xb * E_;
        const unsigned short* hb_ = hbR + (size_t)T_ * (B_ * E_) + xb * E_;
        for (int kc = 0; kc < 128; ++kc) {
            unsigned long long v = *(const unsigned long long*)(hf_ + kc * 4);
            accv = fmaf(wr[kc * 4 + 0], bfbits2f((unsigned)(v & 0xffff)), accv);
            accv = fmaf(wr[kc * 4 + 1], bfbits2f((unsigned)((v >> 16) & 0xffff)), accv);
            accv = fmaf(wr[kc * 4 + 2], bfbits2f((unsigned)((v >> 32) & 0xffff)), accv);
            accv = fmaf(wr[kc * 4 + 3], bfbits2f((unsigned)((v >> 48) & 0xffff)), accv);
        }
        for (int kc = 0; kc < 128; ++kc) {
            unsigned long long v = *(const unsigned long long*)(hb_ + kc * 4);
            accv = fmaf(wr[E_ + kc * 4 + 0], bfbits2f((unsigned)(v & 0xffff)), accv);
            accv = fmaf(wr[E_ + kc * 4 + 1], bfbits2f((unsigned)((v >> 16) & 0xffff)), accv);
            accv = fmaf(wr[E_ + kc * 4 + 2], bfbits2f((unsigned)((v >> 32) & 0xffff)), accv);
            accv = fmaf(wr[E_ + kc * 4 + 3], bfbits2f((unsigned)((v >> 48) & 0xffff)), accv);
        }
        astore_f(&xp0T[r * B_ + xb], accv);
        __syncthreads();         // drain xp0 stores
        if (tid == 0) astore_u32(slotsX + bid, 1u);
        if (bid >= 64) return;
        if (tid < 64) {
            bool ok;
            do {
                ok = (aload_u32(slotsX + tid) != 0u) && (aload_u32(slotsX + 64 + tid) != 0u);
            } while (!__all(ok));
        }
        __syncthreads();
    }

    // ================= decoder: 64 blocks x 4 f-dims (MFMA) =================
    {
        const int fb0 = bid * 4;
        const int ntD = w & 3, kh = w >> 2;      // N-tile, K-half per wave
        const int bcolD = ntD * 16 + col;
        const unsigned short* aDh = dwhH + col * LDK_X + kh * 128 + quad * 8;
        const unsigned short* aDl = dwhL + col * LDK_X + kh * 128 + quad * 8;

        const int ej = tid & 3, eb = tid >> 2;   // epilogue (j,b) for tid<256
        float xg0 = 0, xg1 = 0, xg2 = 0, xg3 = 0;
        if (tid < 256) {
            xg0 = xp0T[(0 * F_ + fb0 + ej) * B_ + eb];
            xg1 = xp0T[(1 * F_ + fb0 + ej) * B_ + eb];
            xg2 = xp0T[(2 * F_ + fb0 + ej) * B_ + eb];
            xg3 = xp0T[(3 * F_ + fb0 + ej) * B_ + eb];
        }
        float creg = 0.0f;

        for (int t = 0; t < T_; ++t) {
            f32x4 acc = {0.f, 0.f, 0.f, 0.f};
            const unsigned long long* h64 = (const unsigned long long*)
                (hdR + (size_t)t * (B_ * F_) + bcolD * F_ + kh * 128 + quad * 8);
            unsigned long long hv[8];
            #pragma unroll
            for (int i = 0; i < 4; ++i) {
                hv[2 * i]     = aload_u64(h64 + i * 8);
                hv[2 * i + 1] = aload_u64(h64 + i * 8 + 1);
            }
            for (;;) {
                bool ok = true;
                #pragma unroll
                for (int i = 0; i < 8; ++i) ok &= (hv[i] != P64);
                if (ok) break;
                #pragma unroll
                for (int i = 0; i < 4; ++i) {
                    hv[2 * i]     = aload_u64(h64 + i * 8);
                    hv[2 * i + 1] = aload_u64(h64 + i * 8 + 1);
                }
            }
            #pragma unroll
            for (int kt = 0; kt < 4; ++kt) {
                bf16x8 hb = mk_bf16x8(hv[2 * kt], hv[2 * kt + 1]);
                bf16x8 ah = *(const bf16x8*)(aDh + kt * 32);
                bf16x8 al = *(const bf16x8*)(aDl + kt * 32);
                acc = __builtin_amdgcn_mfma_f32_16x16x32_bf16(ah, hb, acc, 0, 0, 0);
                acc = __builtin_amdgcn_mfma_f32_16x16x32_bf16(al, hb, acc, 0, 0, 0);
            }
            #pragma unroll
            for (int rg = 0; rg < 4; ++rg)
                pre[kh * (16 * LDP) + (quad * 4 + rg) * LDP + ntD * 16 + col] = acc[rg];
            __syncthreads();

            if (tid < 256) {
                float gI = pre[(0 * 4 + ej) * LDP + eb] + pre[16 * LDP + (0 * 4 + ej) * LDP + eb] + xg0;
                float gF = pre[(1 * 4 + ej) * LDP + eb] + pre[16 * LDP + (1 * 4 + ej) * LDP + eb] + xg1;
                float gG = pre[(2 * 4 + ej) * LDP + eb] + pre[16 * LDP + (2 * 4 + ej) * LDP + eb] + xg2;
                float gO = pre[(3 * 4 + ej) * LDP + eb] + pre[16 * LDP + (3 * 4 + ej) * LDP + eb] + xg3;
                creg = sigmoidf_(gF) * creg + sigmoidf_(gI) * tanhf_(gG);
                float h = sigmoidf_(gO) * tanhf_(creg);
                hpack[eb * 4 + ej] = f2bf(h);
                out[(size_t)t * B_ * F_ + (size_t)eb * F_ + fb0 + ej] = h;
            }
            __syncthreads();
            if (tid < 64) {      // fire-and-forget data-as-flag store
                unsigned long long* dst = (unsigned long long*)
                    (hdR + (size_t)(t + 1) * (B_ * F_) + tid * F_ + fb0);
                astore_u64(dst, ((const unsigned long long*)hpack)[tid]);
            }
        }
    }
}

extern "C" void kernel_launch(void* const* d_in, const int* in_sizes, int n_in,
                              void* d_out, int out_size, void* d_ws, size_t ws_size,
                              hipStream_t stream) {
    const float* seq  = (const float*)d_in[0];
    const float* WihF = (const float*)d_in[1];
    const float* WhhF = (const float*)d_in[2];
    const float* bF   = (const float*)d_in[3];
    const float* WihB = (const float*)d_in[4];
    const float* WhhB = (const float*)d_in[5];
    const float* bB   = (const float*)d_in[6];
    const float* dWih = (const float*)d_in[7];
    const float* dWhh = (const float*)d_in[8];
    const float* db   = (const float*)d_in[9];
    float* out = (float*)d_out;
    char* ws   = (char*)d_ws;

    void* args[] = { &seq, &WihF, &WhhF, &bF, &WihB, &WhhB, &bB,
                     &dWih, &dWhh, &db, &out, &ws };
    hipLaunchCooperativeKernel((void*)autoenc_kernel, dim3(128), dim3(512),
                               args, 0, stream);
}